// Round 6
// baseline (495.299 us; speedup 1.0000x reference)
//
#include <hip/hip_runtime.h>
#include <hip/hip_bf16.h>

#define DIM 1024
#define NHEADS 16
#define HDIM 64
#define FF_ 4096
#define BB 8
#define TT 512
#define SS 4096

typedef __attribute__((ext_vector_type(8))) __bf16 bf16x8;
typedef __attribute__((ext_vector_type(4))) float f32x4;
typedef __attribute__((ext_vector_type(4))) unsigned short us4;

#define SWZ(r, b) ((b) ^ (((r) & 7) << 4))

typedef const __attribute__((address_space(1))) void gvoid_t;
typedef __attribute__((address_space(3))) void lvoid_t;

__device__ __forceinline__ void ldst16(const void* g, void* l) {
  __builtin_amdgcn_global_load_lds((gvoid_t*)g, (lvoid_t*)l, 16, 0, 0);
}

__device__ inline unsigned short f2bf(float f) {
  unsigned u = __float_as_uint(f);
  u += 0x7fff + ((u >> 16) & 1);   // RNE
  return (unsigned short)(u >> 16);
}

__device__ __forceinline__ unsigned cvt_pk(float lo, float hi) {
  unsigned r;
  asm("v_cvt_pk_bf16_f32 %0, %1, %2" : "=v"(r) : "v"(lo), "v"(hi));
  return r;
}

// ---------------------------------------------------------------------------
// f32 -> bf16 vectorized convert (n4 = count/4)
// ---------------------------------------------------------------------------
__global__ void cvt_f32_bf16(const float* __restrict__ in,
                             unsigned short* __restrict__ out, int n4) {
  int i = blockIdx.x * blockDim.x + threadIdx.x;
  int stride = gridDim.x * blockDim.x;
  for (; i < n4; i += stride) {
    float4 v = ((const float4*)in)[i];
    uint2 w = {cvt_pk(v.x, v.y), cvt_pk(v.z, v.w)};
    ((uint2*)out)[i] = w;
  }
}

// ---------------------------------------------------------------------------
// transpose + cast: in f32 [R][C] -> out bf16 [C][R]
// ---------------------------------------------------------------------------
__global__ void transpose_f32_bf16(const float* __restrict__ in,
                                   unsigned short* __restrict__ out,
                                   int R, int C) {
  __shared__ float tile[32][33];
  int bc = blockIdx.x * 32, br = blockIdx.y * 32;
  int tx = threadIdx.x & 31, ty = threadIdx.x >> 5;  // 32 x 8
#pragma unroll
  for (int i = 0; i < 32; i += 8)
    tile[ty + i][tx] = in[(size_t)(br + ty + i) * C + bc + tx];
  __syncthreads();
#pragma unroll
  for (int i = 0; i < 32; i += 8)
    out[(size_t)(bc + ty + i) * R + br + tx] = f2bf(tile[tx][ty + i]);
}

// ---------------------------------------------------------------------------
// GEMM 128x128 (2-barrier m97 structure) for small GEMMs.
// EPI: 0 = bf16 store; 1 = tanh-GELU -> bf16; 2 = +res -> f32;
//      3 = +res -> f32 (C) AND bf16 (C2)
// ---------------------------------------------------------------------------
template <int EPI>
__global__ __launch_bounds__(256, 3)
void gemm_kernel(const unsigned short* __restrict__ A,
                 const unsigned short* __restrict__ Bt,
                 const float* __restrict__ bias,
                 const float* __restrict__ res,
                 void* __restrict__ Cp,
                 unsigned short* __restrict__ C2,
                 int M, int N, int K) {
  __shared__ char smem[32768];
  char* As = smem;
  char* Bs = smem + 16384;

  const int tid = threadIdx.x;
  const int lane = tid & 63;
  const int wave = tid >> 6;
  const int wm = wave >> 1, wn = wave & 1;

  const int flat = blockIdx.y * gridDim.x + blockIdx.x;
  const int cpx = (gridDim.x * gridDim.y) >> 3;
  const int swz = (flat & 7) * cpx + (flat >> 3);
  const int m0 = (swz / gridDim.x) * 128, n0 = (swz % gridDim.x) * 128;

  f32x4 acc[4][4];
#pragma unroll
  for (int i = 0; i < 4; ++i)
#pragma unroll
    for (int j = 0; j < 4; ++j) acc[i][j] = (f32x4){0.f, 0.f, 0.f, 0.f};

  for (int k0 = 0; k0 < K; k0 += 64) {
    __syncthreads();
#pragma unroll
    for (int i = 0; i < 4; ++i) {
      int ch = (wave * 4 + i) * 64 + lane;
      int r = ch >> 3, c8 = (ch & 7) ^ (r & 7);
      ldst16(A + (size_t)(m0 + r) * K + k0 + c8 * 8, As + (wave * 4 + i) * 1024);
      ldst16(Bt + (size_t)(n0 + r) * K + k0 + c8 * 8, Bs + (wave * 4 + i) * 1024);
    }
    __syncthreads();

#pragma unroll
    for (int kk = 0; kk < 2; ++kk) {
      bf16x8 a[4], b[4];
#pragma unroll
      for (int mi = 0; mi < 4; ++mi) {
        int r = wm * 64 + mi * 16 + (lane & 15);
        a[mi] = *(const bf16x8*)(As + r * 128 + SWZ(r, kk * 64 + (lane >> 4) * 16));
      }
#pragma unroll
      for (int ni = 0; ni < 4; ++ni) {
        int r = wn * 64 + ni * 16 + (lane & 15);
        b[ni] = *(const bf16x8*)(Bs + r * 128 + SWZ(r, kk * 64 + (lane >> 4) * 16));
      }
#pragma unroll
      for (int mi = 0; mi < 4; ++mi)
#pragma unroll
        for (int ni = 0; ni < 4; ++ni)
          acc[mi][ni] = __builtin_amdgcn_mfma_f32_16x16x32_bf16(b[ni], a[mi], acc[mi][ni], 0, 0, 0);
    }
  }

  const int q = lane & 15, g4 = (lane >> 4) * 4;
#pragma unroll
  for (int mi = 0; mi < 4; ++mi) {
    int row = m0 + wm * 64 + mi * 16 + q;
#pragma unroll
    for (int ni = 0; ni < 4; ++ni) {
      int colb = n0 + wn * 64 + ni * 16 + g4;
      float4 bv = *(const float4*)(bias + colb);
      f32x4 v = acc[mi][ni];
      float v0 = v[0] + bv.x, v1 = v[1] + bv.y, v2 = v[2] + bv.z, v3 = v[3] + bv.w;
      if (EPI == 0) {
        uint2 w = {cvt_pk(v0, v1), cvt_pk(v2, v3)};
        *(uint2*)((unsigned short*)Cp + (size_t)row * N + colb) = w;
      } else if (EPI == 1) {
        float o[4] = {v0, v1, v2, v3};
#pragma unroll
        for (int j = 0; j < 4; ++j) {
          float u = 0.7978845608028654f * (o[j] + 0.044715f * o[j] * o[j] * o[j]);
          float e = __expf(2.f * u);
          float th = 1.f - 2.f / (e + 1.f);
          o[j] = 0.5f * o[j] * (1.f + th);
        }
        uint2 w = {cvt_pk(o[0], o[1]), cvt_pk(o[2], o[3])};
        *(uint2*)((unsigned short*)Cp + (size_t)row * N + colb) = w;
      } else {
        float4 r4 = *(const float4*)(res + (size_t)row * N + colb);
        float o0 = v0 + r4.x, o1 = v1 + r4.y, o2 = v2 + r4.z, o3 = v3 + r4.w;
        float4 ov = {o0, o1, o2, o3};
        *(float4*)((float*)Cp + (size_t)row * N + colb) = ov;
        if (EPI == 3) {
          uint2 w = {cvt_pk(o0, o1), cvt_pk(o2, o3)};
          *(uint2*)(C2 + (size_t)row * N + colb) = w;
        }
      }
    }
  }
}

// ---------------------------------------------------------------------------
// GEMM 256x256, BK=64, 512 threads (2x4 waves, 128x64 per wave).
// 4 phases/K-tile, sound region schedule (retirement-derived):
//   B(cb) free after p0 (reg-resident)  -> stage B(kt+2) @ p1, p2
//   A(cb) free after p3                 -> stage A(kt+1) h0+h1 @ p0
// vmcnt(4) once per K-tile (drains A(kt+1), keeps B(kt+2) in flight);
// vmcnt(0) only at tail. ds_reads issued before stage; raw barriers;
// setprio around MFMA cluster.
// EPI: 1 = tanh-GELU -> bf16 (Cp, ld N)
//      2 = KV split: n0<1024 -> bf16 into Cp (ld 1024); else transposed
//          V write into C2 = Vt[b][d][s]
// ---------------------------------------------------------------------------
template <int EPI>
__global__ __launch_bounds__(512, 2)
void gemm256(const unsigned short* __restrict__ A,
             const unsigned short* __restrict__ Bt,
             const float* __restrict__ bias,
             void* __restrict__ Cp,
             unsigned short* __restrict__ C2,
             int M, int N, int K) {
  __shared__ char smem[131072];
  // A: buf0 0..32K buf1 32..64K | B: buf0 64..96K buf1 96..128K

  const int tid = threadIdx.x, lane = tid & 63, wave = tid >> 6;
  const int q = lane & 15, g = lane >> 4;
  const int wm = wave >> 2, wn = wave & 3;

  const int flat = blockIdx.y * gridDim.x + blockIdx.x;
  const int cpx = (gridDim.x * gridDim.y) >> 3;
  const int swz = (flat & 7) * cpx + (flat >> 3);
  const int m0 = (swz / gridDim.x) * 256, n0 = (swz % gridDim.x) * 256;

  const unsigned short* Arow = A + (size_t)m0 * K;
  const unsigned short* Brow = Bt + (size_t)n0 * K;

  const int r0 = tid >> 3, c0 = ((tid & 7) ^ (r0 & 7)) * 8;                  // rows 0..63
  const int r1 = (tid + 512) >> 3, c1 = (((tid + 512) & 7) ^ (r1 & 7)) * 8;  // 64..127

#define STA(buf, half, kt)                                                     \
  { char* d = smem + (buf) * 32768 + (half) * 16384;                           \
    const unsigned short* s = Arow + (size_t)((half) * 128) * K + (kt) * 64;   \
    ldst16(s + (size_t)r0 * K + c0, d + tid * 16);                             \
    ldst16(s + (size_t)r1 * K + c1, d + 8192 + tid * 16); }
#define STB(buf, half, kt)                                                     \
  { char* d = smem + 65536 + (buf) * 32768 + (half) * 16384;                   \
    const unsigned short* s = Brow + (size_t)((half) * 128) * K + (kt) * 64;   \
    ldst16(s + (size_t)r0 * K + c0, d + tid * 16);                             \
    ldst16(s + (size_t)r1 * K + c1, d + 8192 + tid * 16); }

  f32x4 acc[8][4];
#pragma unroll
  for (int i = 0; i < 8; ++i)
#pragma unroll
    for (int j = 0; j < 4; ++j) acc[i][j] = (f32x4){0.f, 0.f, 0.f, 0.f};

  // prologue: kt0 (A+B) + B(kt1). A(kt1) staged at kt0-p0.
  STA(0, 0, 0); STA(0, 1, 0); STB(0, 0, 0); STB(0, 1, 0);
  STB(1, 0, 1); STB(1, 1, 1);
  asm volatile("s_waitcnt vmcnt(4)" ::: "memory");   // drain kt0 (8 loads)
  __builtin_amdgcn_s_barrier();

  const int NKT = K >> 6;
  for (int kt = 0; kt < NKT; ++kt) {
    const int cb = kt & 1, nb = cb ^ 1;
    const char* Ab = smem + cb * 32768;
    const char* Bb = smem + 65536 + cb * 32768;
    bf16x8 bfr[4][2];

#pragma unroll
    for (int p = 0; p < 4; ++p) {
      // ds_read this phase's fragments (before stage; overlaps barrier skew)
      bf16x8 af[2][2];
#pragma unroll
      for (int i = 0; i < 2; ++i)
#pragma unroll
        for (int kk = 0; kk < 2; ++kk) {
          int r = wm * 128 + (2 * p + i) * 16 + q;
          af[i][kk] = *(const bf16x8*)(Ab + r * 128 + SWZ(r, kk * 64 + g * 16));
        }
      if (p == 0) {
#pragma unroll
        for (int nr = 0; nr < 4; ++nr)
#pragma unroll
          for (int kk = 0; kk < 2; ++kk) {
            int r = wn * 64 + nr * 16 + q;
            bfr[nr][kk] = *(const bf16x8*)(Bb + r * 128 + SWZ(r, kk * 64 + g * 16));
          }
      }

      // stage (regions freed by retirement analysis above)
      if (p == 0)      { if (kt + 1 < NKT) { STA(nb, 0, kt + 1); STA(nb, 1, kt + 1); } }
      else if (p == 1) { if (kt + 2 < NKT) STB(cb, 0, kt + 2); }
      else if (p == 2) { if (kt + 2 < NKT) STB(cb, 1, kt + 2); }

      __builtin_amdgcn_s_barrier();
      asm volatile("s_waitcnt lgkmcnt(0)" ::: "memory");
      __builtin_amdgcn_sched_barrier(0);
      __builtin_amdgcn_s_setprio(1);
#pragma unroll
      for (int i = 0; i < 2; ++i)
#pragma unroll
        for (int nr = 0; nr < 4; ++nr)
#pragma unroll
          for (int kk = 0; kk < 2; ++kk)
            acc[2 * p + i][nr] = __builtin_amdgcn_mfma_f32_16x16x32_bf16(
                bfr[nr][kk], af[i][kk], acc[2 * p + i][nr], 0, 0, 0);
      __builtin_amdgcn_s_setprio(0);

      if (p == 3) {
        if (kt + 2 < NKT) { asm volatile("s_waitcnt vmcnt(4)" ::: "memory"); }
        else              { asm volatile("s_waitcnt vmcnt(0)" ::: "memory"); }
      }
      __builtin_amdgcn_s_barrier();
    }
  }

  // epilogue
  const int g4 = g * 4;
#pragma unroll
  for (int mr = 0; mr < 8; ++mr) {
    int row = m0 + wm * 128 + mr * 16 + q;
#pragma unroll
    for (int nr = 0; nr < 4; ++nr) {
      int colb = n0 + wn * 64 + nr * 16 + g4;
      float4 bv = *(const float4*)(bias + colb);
      f32x4 v = acc[mr][nr];
      float v0 = v[0] + bv.x, v1 = v[1] + bv.y, v2 = v[2] + bv.z, v3 = v[3] + bv.w;
      if (EPI == 1) {
        float o[4] = {v0, v1, v2, v3};
#pragma unroll
        for (int j = 0; j < 4; ++j) {
          float u = 0.7978845608028654f * (o[j] + 0.044715f * o[j] * o[j] * o[j]);
          float e = __expf(2.f * u);
          float th = 1.f - 2.f / (e + 1.f);
          o[j] = 0.5f * o[j] * (1.f + th);
        }
        uint2 w = {cvt_pk(o[0], o[1]), cvt_pk(o[2], o[3])};
        *(uint2*)((unsigned short*)Cp + (size_t)row * N + colb) = w;
      } else {  // EPI == 2: KV split
        if (n0 < 1024) {
          uint2 w = {cvt_pk(v0, v1), cvt_pk(v2, v3)};
          *(uint2*)((unsigned short*)Cp + (size_t)row * 1024 + colb) = w;
        } else {
          int b = row >> 12, s = row & 4095;
          int d0 = colb - 1024;
          unsigned short* vt = C2 + ((size_t)b * DIM + d0) * SS + s;
          vt[0] = f2bf(v0);
          vt[SS] = f2bf(v1);
          vt[2 * SS] = f2bf(v2);
          vt[3 * SS] = f2bf(v3);
        }
      }
    }
  }
#undef STA
#undef STB
}

// ---------------------------------------------------------------------------
// Flash attention v4 (swapped-operand, no-max softmax, 512 threads).
// Triple-buffered K/V: stage t+2 during t; raw s_barrier + vmcnt(2)
// (never 0 in steady state) — no full drain per tile.
// Grid 512 linear: b = bid&7 (batch->XCD), qt = (bid>>3)&3, h = bid>>5.
// LDS 80KB -> 2 blocks/CU.
// ---------------------------------------------------------------------------
__global__ __launch_bounds__(512, 4)
void attn_kernel4(const unsigned short* __restrict__ Qb,
                  const unsigned short* __restrict__ Kb,
                  const unsigned short* __restrict__ Vt,
                  unsigned short* __restrict__ Ob) {
  __shared__ char smem[81920];
  // Qs 0..16K | Ks 3 bufs @16K+j*8K | Vs 3 bufs @40K+j*8K | Ps 64K (8x2KB)

  const int tid = threadIdx.x, lane = tid & 63, wave = tid >> 6;
  const int bid = blockIdx.x;
  const int b = bid & 7, qt = (bid >> 3) & 3, h = bid >> 5;
  const int q0 = qt * 128;
  const int q = lane & 15, g = lane >> 4;

  const int rK = tid >> 3;
  const int cK = (tid & 7) ^ (rK & 7);
  char* const Pw = smem + 65536 + wave * 2048;

  const unsigned short* srcQ = Qb + ((size_t)b * TT + q0) * DIM + h * HDIM;
  const unsigned short* srcK = Kb + (size_t)b * SS * DIM + h * HDIM;
  const unsigned short* srcV = Vt + ((size_t)b * DIM + h * HDIM) * SS;

  // prologue: Q (2 chunks) + K/V tiles 0 and 1
  {
    int r = tid >> 3, c = (tid & 7) ^ (r & 7);
    ldst16(srcQ + (size_t)r * DIM + c * 8, smem + tid * 16);
    int ch = tid + 512;
    r = ch >> 3; c = (ch & 7) ^ (r & 7);
    ldst16(srcQ + (size_t)r * DIM + c * 8, smem + ch * 16);
  }
  ldst16(srcK + (size_t)rK * DIM + cK * 8, smem + 16384 + tid * 16);
  ldst16(srcV + (size_t)rK * SS + cK * 8, smem + 40960 + tid * 16);
  ldst16(srcK + (size_t)(64 + rK) * DIM + cK * 8, smem + 24576 + tid * 16);
  ldst16(srcV + (size_t)rK * SS + 64 + cK * 8, smem + 49152 + tid * 16);
  asm volatile("s_waitcnt vmcnt(2)" ::: "memory");   // Q + tile0 done
  __builtin_amdgcn_s_barrier();

  bf16x8 qf[2];
  {
    int r = wave * 16 + q;
    qf[0] = *(const bf16x8*)(smem + r * 128 + SWZ(r, g * 16));
    qf[1] = *(const bf16x8*)(smem + r * 128 + SWZ(r, 64 + g * 16));
  }

  f32x4 acc[4];
#pragma unroll
  for (int dt = 0; dt < 4; ++dt) acc[dt] = (f32x4){0.f, 0.f, 0.f, 0.f};
  float lsum = 0.f;
  const float CSC = 0.125f * 1.4426950408889634f;

  const int NT = SS / 64;
  int cur = 0, sb = 2;
  for (int t = 0; t < NT; ++t) {
    char* Kc = smem + 16384 + cur * 8192;
    char* Vc = smem + 40960 + cur * 8192;
    if (t + 2 < NT) {
      char* Kn = smem + 16384 + sb * 8192;
      char* Vn = smem + 40960 + sb * 8192;
      ldst16(srcK + (size_t)((t + 2) * 64 + rK) * DIM + cK * 8, Kn + tid * 16);
      ldst16(srcV + (size_t)rK * SS + (t + 2) * 64 + cK * 8, Vn + tid * 16);
    }

    f32x4 st[4];
#pragma unroll
    for (int si = 0; si < 4; ++si) st[si] = (f32x4){0.f, 0.f, 0.f, 0.f};
#pragma unroll
    for (int kk = 0; kk < 2; ++kk)
#pragma unroll
      for (int si = 0; si < 4; ++si) {
        int r = si * 16 + q;
        bf16x8 kf = *(const bf16x8*)(Kc + r * 128 + SWZ(r, kk * 64 + g * 16));
        st[si] = __builtin_amdgcn_mfma_f32_16x16x32_bf16(kf, qf[kk], st[si], 0, 0, 0);
      }

    float rs = 0.f;
#pragma unroll
    for (int si = 0; si < 4; ++si) {
      float p0 = __builtin_amdgcn_exp2f(st[si][0] * CSC);
      float p1 = __builtin_amdgcn_exp2f(st[si][1] * CSC);
      float p2 = __builtin_amdgcn_exp2f(st[si][2] * CSC);
      float p3 = __builtin_amdgcn_exp2f(st[si][3] * CSC);
      rs += (p0 + p1) + (p2 + p3);
      uint2 w = {cvt_pk(p0, p1), cvt_pk(p2, p3)};
      *(uint2*)(Pw + q * 128 + SWZ(q, si * 32 + g * 8)) = w;
    }
    lsum += rs;

#pragma unroll
    for (int kk = 0; kk < 2; ++kk) {
      bf16x8 pb = *(const bf16x8*)(Pw + q * 128 + SWZ(q, kk * 64 + g * 16));
#pragma unroll
      for (int dt = 0; dt < 4; ++dt) {
        int r = dt * 16 + q;
        bf16x8 va = *(const bf16x8*)(Vc + r * 128 + SWZ(r, kk * 64 + g * 16));
        acc[dt] = __builtin_amdgcn_mfma_f32_16x16x32_bf16(va, pb, acc[dt], 0, 0, 0);
      }
    }

    if (t + 2 < NT) { asm volatile("s_waitcnt vmcnt(2)" ::: "memory"); }
    else            { asm volatile("s_waitcnt vmcnt(0)" ::: "memory"); }
    __builtin_amdgcn_s_barrier();
    cur = cur == 2 ? 0 : cur + 1;
    sb  = sb  == 2 ? 0 : sb  + 1;
  }

  lsum += __shfl_xor(lsum, 16);
  lsum += __shfl_xor(lsum, 32);
  float inv = 1.0f / lsum;
#pragma unroll
  for (int dt = 0; dt < 4; ++dt) {
    f32x4 v = acc[dt];
    uint2 w = {cvt_pk(v[0] * inv, v[1] * inv), cvt_pk(v[2] * inv, v[3] * inv)};
    *(uint2*)(Pw + q * 128 + SWZ(q, dt * 32 + g * 8)) = w;
  }
  __builtin_amdgcn_s_waitcnt(0);
  int qr = lane >> 2, cb = (lane & 3) * 32;
  uint4 lo = *(const uint4*)(Pw + qr * 128 + SWZ(qr, cb));
  uint4 hi = *(const uint4*)(Pw + qr * 128 + SWZ(qr, cb + 16));
  size_t ob = ((size_t)b * TT + q0 + wave * 16 + qr) * DIM + h * HDIM + (lane & 3) * 16;
  *(uint4*)(Ob + ob) = lo;
  *(uint4*)(Ob + ob + 8) = hi;
}

// ---------------------------------------------------------------------------
// host
// ---------------------------------------------------------------------------
extern "C" void kernel_launch(void* const* d_in, const int* in_sizes, int n_in,
                              void* d_out, int out_size, void* d_ws, size_t ws_size,
                              hipStream_t stream) {
  const float* x   = (const float*)d_in[0];
  const float* inp = (const float*)d_in[1];
  const float* Wq  = (const float*)d_in[2];
  const float* bq  = (const float*)d_in[3];
  const float* Wk  = (const float*)d_in[4];
  const float* bk  = (const float*)d_in[5];
  const float* Wv  = (const float*)d_in[6];
  const float* bv  = (const float*)d_in[7];
  const float* Wo  = (const float*)d_in[8];
  const float* bo  = (const float*)d_in[9];
  const float* W1  = (const float*)d_in[10];
  const float* b1  = (const float*)d_in[11];
  const float* W2  = (const float*)d_in[12];
  const float* b2  = (const float*)d_in[13];
  float* out = (float*)d_out;

  // workspace (MB): 0-2 Wqt | 2-6 Wkvt | 6-8 Wot | 8-16 W1t | 16-24 W2t |
  // 24 bkv | 25-33 Qb | 33-97 Kb | 97-161 Vt | 161-225 inpb | 225-233 xb
  // post-attn: x2 33-49 (f32) | x2b 49-57 | hb 57-89. Obf aliases d_out.
  char* ws = (char*)d_ws;
  const size_t MB = 1024ull * 1024ull;
  unsigned short* Wqt  = (unsigned short*)(ws + 0 * MB);
  unsigned short* Wkt  = (unsigned short*)(ws + 2 * MB);
  unsigned short* Wvt  = (unsigned short*)(ws + 4 * MB);
  unsigned short* Wkvt = Wkt;                                // [2048][1024]
  unsigned short* Wot  = (unsigned short*)(ws + 6 * MB);
  unsigned short* W1t  = (unsigned short*)(ws + 8 * MB);
  unsigned short* W2t  = (unsigned short*)(ws + 16 * MB);
  float*          bkv  = (float*)(ws + 24 * MB);
  unsigned short* Qb   = (unsigned short*)(ws + 25 * MB);
  unsigned short* Kb   = (unsigned short*)(ws + 33 * MB);
  float*          x2   = (float*)(ws + 33 * MB);             // post-attn alias
  unsigned short* x2b  = (unsigned short*)(ws + 49 * MB);
  unsigned short* hb   = (unsigned short*)(ws + 57 * MB);
  unsigned short* Vt   = (unsigned short*)(ws + 97 * MB);
  unsigned short* inpb = (unsigned short*)(ws + 161 * MB);
  unsigned short* xb   = (unsigned short*)(ws + 225 * MB);
  unsigned short* Obf  = (unsigned short*)d_out;

  hipMemcpyAsync(bkv, bk, 1024 * sizeof(float), hipMemcpyDeviceToDevice, stream);
  hipMemcpyAsync(bkv + 1024, bv, 1024 * sizeof(float), hipMemcpyDeviceToDevice, stream);

  cvt_f32_bf16<<<2048, 256, 0, stream>>>(inp, inpb, BB * SS * DIM / 4);
  cvt_f32_bf16<<<1024, 256, 0, stream>>>(x, xb, BB * TT * DIM / 4);

  transpose_f32_bf16<<<dim3(32, 32), 256, 0, stream>>>(Wq, Wqt, 1024, 1024);
  transpose_f32_bf16<<<dim3(32, 32), 256, 0, stream>>>(Wk, Wkt, 1024, 1024);
  transpose_f32_bf16<<<dim3(32, 32), 256, 0, stream>>>(Wv, Wvt, 1024, 1024);
  transpose_f32_bf16<<<dim3(32, 32), 256, 0, stream>>>(Wo, Wot, 1024, 1024);
  transpose_f32_bf16<<<dim3(128, 32), 256, 0, stream>>>(W1, W1t, 1024, 4096);
  transpose_f32_bf16<<<dim3(32, 128), 256, 0, stream>>>(W2, W2t, 4096, 1024);

  // Q projection (128^2)
  gemm_kernel<0><<<dim3(8, 32), 256, 0, stream>>>(xb, Wqt, bq, nullptr, Qb, nullptr, BB * TT, DIM, DIM);
  // fused KV projection (256^2 4-phase): K-half -> Kb, V-half -> Vt transposed
  gemm256<2><<<dim3(8, 128), 512, 0, stream>>>(inpb, Wkvt, bkv, Kb, Vt, BB * SS, 2048, DIM);

  attn_kernel4<<<dim3(512), 512, 0, stream>>>(Qb, Kb, Vt, Obf);

  // O projection + residual -> x2 (f32) + x2b (bf16)
  gemm_kernel<3><<<dim3(8, 32), 256, 0, stream>>>(Obf, Wot, bo, x, x2, x2b, BB * TT, DIM, DIM);
  // MLP1 (256^2 4-phase, GELU)
  gemm256<1><<<dim3(16, 16), 512, 0, stream>>>(x2b, W1t, b1, hb, nullptr, BB * TT, FF_, DIM);
  // MLP2 (128^2, +res f32)
  gemm_kernel<2><<<dim3(8, 32), 256, 0, stream>>>(hb, W2t, b2, x2, out, nullptr, BB * TT, DIM, FF_);
}

// Round 7
// 449.719 us; speedup vs baseline: 1.1014x; 1.1014x over previous
//
#include <hip/hip_runtime.h>
#include <hip/hip_bf16.h>

#define DIM 1024
#define NHEADS 16
#define HDIM 64
#define FF_ 4096
#define BB 8
#define TT 512
#define SS 4096

typedef __attribute__((ext_vector_type(8))) __bf16 bf16x8;
typedef __attribute__((ext_vector_type(4))) float f32x4;
typedef __attribute__((ext_vector_type(4))) unsigned short us4;

#define SWZ(r, b) ((b) ^ (((r) & 7) << 4))

typedef const __attribute__((address_space(1))) void gvoid_t;
typedef __attribute__((address_space(3))) void lvoid_t;

__device__ __forceinline__ void ldst16(const void* g, void* l) {
  __builtin_amdgcn_global_load_lds((gvoid_t*)g, (lvoid_t*)l, 16, 0, 0);
}

__device__ inline unsigned short f2bf(float f) {
  unsigned u = __float_as_uint(f);
  u += 0x7fff + ((u >> 16) & 1);   // RNE
  return (unsigned short)(u >> 16);
}

__device__ __forceinline__ unsigned cvt_pk(float lo, float hi) {
  unsigned r;
  asm("v_cvt_pk_bf16_f32 %0, %1, %2" : "=v"(r) : "v"(lo), "v"(hi));
  return r;
}

// ---------------------------------------------------------------------------
// Mega-prep: ONE launch does all input converts + weight transposes + bias
// concat (replaces 10 graph nodes with 1).
// block ranges:
//   [0,2048)      cvt inp -> inpb (8M float4, grid-stride)
//   [2048,2304)   cvt x -> xb (1M float4)
//   [2304,3328)   Wq^T -> Wqt        (1024 tiles 32x32)
//   [3328,4352)   Wk^T -> Wkvt[0:1024]
//   [4352,5376)   Wv^T -> Wkvt[1024:2048]
//   [5376,6400)   Wo^T -> Wot
//   [6400,10496)  W1^T -> W1t        (4096 tiles; C=4096)
//   [10496,14592) W2^T -> W2t        (4096 tiles; R=4096)
//   14592         bkv = concat(bk,bv)
// ---------------------------------------------------------------------------
__global__ void prep_kernel(const float* __restrict__ x,
                            const float* __restrict__ inp,
                            const float* __restrict__ Wq,
                            const float* __restrict__ Wk,
                            const float* __restrict__ Wv,
                            const float* __restrict__ Wo,
                            const float* __restrict__ W1,
                            const float* __restrict__ W2,
                            const float* __restrict__ bk,
                            const float* __restrict__ bv,
                            unsigned short* __restrict__ xb,
                            unsigned short* __restrict__ inpb,
                            unsigned short* __restrict__ Wqt,
                            unsigned short* __restrict__ Wkvt,
                            unsigned short* __restrict__ Wot,
                            unsigned short* __restrict__ W1t,
                            unsigned short* __restrict__ W2t,
                            float* __restrict__ bkv) {
  __shared__ float tile[32][33];
  const int bid = blockIdx.x, tid = threadIdx.x;

  if (bid < 2048) {            // inp convert
    const int n4 = BB * SS * DIM / 4;
    for (int i = bid * 256 + tid; i < n4; i += 2048 * 256) {
      float4 v = ((const float4*)inp)[i];
      uint2 w = {cvt_pk(v.x, v.y), cvt_pk(v.z, v.w)};
      ((uint2*)inpb)[i] = w;
    }
    return;
  }
  if (bid < 2304) {            // x convert
    const int n4 = BB * TT * DIM / 4;
    for (int i = (bid - 2048) * 256 + tid; i < n4; i += 256 * 256) {
      float4 v = ((const float4*)x)[i];
      uint2 w = {cvt_pk(v.x, v.y), cvt_pk(v.z, v.w)};
      ((uint2*)xb)[i] = w;
    }
    return;
  }
  if (bid < 14592) {           // weight transposes
    const float* in;
    unsigned short* outp;
    int R, C, t, tilesx;
    if (bid < 3328)       { in = Wq; outp = Wqt; R = 1024; C = 1024; t = bid - 2304; tilesx = 32; }
    else if (bid < 4352)  { in = Wk; outp = Wkvt; R = 1024; C = 1024; t = bid - 3328; tilesx = 32; }
    else if (bid < 5376)  { in = Wv; outp = Wkvt + 1024 * 1024; R = 1024; C = 1024; t = bid - 4352; tilesx = 32; }
    else if (bid < 6400)  { in = Wo; outp = Wot; R = 1024; C = 1024; t = bid - 5376; tilesx = 32; }
    else if (bid < 10496) { in = W1; outp = W1t; R = 1024; C = 4096; t = bid - 6400; tilesx = 128; }
    else                  { in = W2; outp = W2t; R = 4096; C = 1024; t = bid - 10496; tilesx = 32; }
    int bc = (t % tilesx) * 32, br = (t / tilesx) * 32;
    int tx = tid & 31, ty = tid >> 5;  // 32 x 8
#pragma unroll
    for (int i = 0; i < 32; i += 8)
      tile[ty + i][tx] = in[(size_t)(br + ty + i) * C + bc + tx];
    __syncthreads();
#pragma unroll
    for (int i = 0; i < 32; i += 8)
      outp[(size_t)(bc + ty + i) * R + br + tx] = f2bf(tile[tx][ty + i]);
    return;
  }
  // bias concat
  for (int i = tid; i < 1024; i += 256) {
    bkv[i] = bk[i];
    bkv[1024 + i] = bv[i];
  }
}

// ---------------------------------------------------------------------------
// GEMM 128x128 (2-barrier m97 structure) for small GEMMs.
// EPI: 0 = bf16 store; 1 = tanh-GELU -> bf16; 2 = +res -> f32;
//      3 = +res -> f32 (C) AND bf16 (C2)
// ---------------------------------------------------------------------------
template <int EPI>
__global__ __launch_bounds__(256, 3)
void gemm_kernel(const unsigned short* __restrict__ A,
                 const unsigned short* __restrict__ Bt,
                 const float* __restrict__ bias,
                 const float* __restrict__ res,
                 void* __restrict__ Cp,
                 unsigned short* __restrict__ C2,
                 int M, int N, int K) {
  __shared__ char smem[32768];
  char* As = smem;
  char* Bs = smem + 16384;

  const int tid = threadIdx.x;
  const int lane = tid & 63;
  const int wave = tid >> 6;
  const int wm = wave >> 1, wn = wave & 1;

  const int flat = blockIdx.y * gridDim.x + blockIdx.x;
  const int cpx = (gridDim.x * gridDim.y) >> 3;
  const int swz = (flat & 7) * cpx + (flat >> 3);
  const int m0 = (swz / gridDim.x) * 128, n0 = (swz % gridDim.x) * 128;

  f32x4 acc[4][4];
#pragma unroll
  for (int i = 0; i < 4; ++i)
#pragma unroll
    for (int j = 0; j < 4; ++j) acc[i][j] = (f32x4){0.f, 0.f, 0.f, 0.f};

  for (int k0 = 0; k0 < K; k0 += 64) {
    __syncthreads();
#pragma unroll
    for (int i = 0; i < 4; ++i) {
      int ch = (wave * 4 + i) * 64 + lane;
      int r = ch >> 3, c8 = (ch & 7) ^ (r & 7);
      ldst16(A + (size_t)(m0 + r) * K + k0 + c8 * 8, As + (wave * 4 + i) * 1024);
      ldst16(Bt + (size_t)(n0 + r) * K + k0 + c8 * 8, Bs + (wave * 4 + i) * 1024);
    }
    __syncthreads();

#pragma unroll
    for (int kk = 0; kk < 2; ++kk) {
      bf16x8 a[4], b[4];
#pragma unroll
      for (int mi = 0; mi < 4; ++mi) {
        int r = wm * 64 + mi * 16 + (lane & 15);
        a[mi] = *(const bf16x8*)(As + r * 128 + SWZ(r, kk * 64 + (lane >> 4) * 16));
      }
#pragma unroll
      for (int ni = 0; ni < 4; ++ni) {
        int r = wn * 64 + ni * 16 + (lane & 15);
        b[ni] = *(const bf16x8*)(Bs + r * 128 + SWZ(r, kk * 64 + (lane >> 4) * 16));
      }
#pragma unroll
      for (int mi = 0; mi < 4; ++mi)
#pragma unroll
        for (int ni = 0; ni < 4; ++ni)
          acc[mi][ni] = __builtin_amdgcn_mfma_f32_16x16x32_bf16(b[ni], a[mi], acc[mi][ni], 0, 0, 0);
    }
  }

  const int q = lane & 15, g4 = (lane >> 4) * 4;
#pragma unroll
  for (int mi = 0; mi < 4; ++mi) {
    int row = m0 + wm * 64 + mi * 16 + q;
#pragma unroll
    for (int ni = 0; ni < 4; ++ni) {
      int colb = n0 + wn * 64 + ni * 16 + g4;
      float4 bv = *(const float4*)(bias + colb);
      f32x4 v = acc[mi][ni];
      float v0 = v[0] + bv.x, v1 = v[1] + bv.y, v2 = v[2] + bv.z, v3 = v[3] + bv.w;
      if (EPI == 0) {
        uint2 w = {cvt_pk(v0, v1), cvt_pk(v2, v3)};
        *(uint2*)((unsigned short*)Cp + (size_t)row * N + colb) = w;
      } else if (EPI == 1) {
        float o[4] = {v0, v1, v2, v3};
#pragma unroll
        for (int j = 0; j < 4; ++j) {
          float u = 0.7978845608028654f * (o[j] + 0.044715f * o[j] * o[j] * o[j]);
          float e = __expf(2.f * u);
          float th = 1.f - 2.f / (e + 1.f);
          o[j] = 0.5f * o[j] * (1.f + th);
        }
        uint2 w = {cvt_pk(o[0], o[1]), cvt_pk(o[2], o[3])};
        *(uint2*)((unsigned short*)Cp + (size_t)row * N + colb) = w;
      } else {
        float4 r4 = *(const float4*)(res + (size_t)row * N + colb);
        float o0 = v0 + r4.x, o1 = v1 + r4.y, o2 = v2 + r4.z, o3 = v3 + r4.w;
        float4 ov = {o0, o1, o2, o3};
        *(float4*)((float*)Cp + (size_t)row * N + colb) = ov;
        if (EPI == 3) {
          uint2 w = {cvt_pk(o0, o1), cvt_pk(o2, o3)};
          *(uint2*)(C2 + (size_t)row * N + colb) = w;
        }
      }
    }
  }
}

// ---------------------------------------------------------------------------
// GEMM 256x256, BK=64, 512 threads (2x4 waves, 128x64 per wave).
// 4 phases/K-tile, counted vmcnt, NO manual lgkm drain (compiler emits
// fine-grained lgkmcnt before each MFMA's first operand use and can
// interleave MFMA with remaining ds_reads).
// Stage schedule (retirement-sound): A(kt+1) @ p0; B(kt+2) h0 @ p1,
// h1 @ p2; vmcnt(4) @ p3 (drains A(kt+1)+B(kt+1), keeps B(kt+2) inflight).
// EPI: 1 = tanh-GELU -> bf16 (Cp, ld N)
//      2 = KV split: n0<1024 -> bf16 into Cp (ld 1024); else transposed
//          V write into C2 = Vt[b][d][s]
// ---------------------------------------------------------------------------
template <int EPI>
__global__ __launch_bounds__(512, 2)
void gemm256(const unsigned short* __restrict__ A,
             const unsigned short* __restrict__ Bt,
             const float* __restrict__ bias,
             void* __restrict__ Cp,
             unsigned short* __restrict__ C2,
             int M, int N, int K) {
  __shared__ char smem[131072];
  // A: buf0 0..32K buf1 32..64K | B: buf0 64..96K buf1 96..128K

  const int tid = threadIdx.x, lane = tid & 63, wave = tid >> 6;
  const int q = lane & 15, g = lane >> 4;
  const int wm = wave >> 2, wn = wave & 3;

  const int flat = blockIdx.y * gridDim.x + blockIdx.x;
  const int cpx = (gridDim.x * gridDim.y) >> 3;
  const int swz = (flat & 7) * cpx + (flat >> 3);
  const int m0 = (swz / gridDim.x) * 256, n0 = (swz % gridDim.x) * 256;

  const unsigned short* Arow = A + (size_t)m0 * K;
  const unsigned short* Brow = Bt + (size_t)n0 * K;

  const int r0 = tid >> 3, c0 = ((tid & 7) ^ (r0 & 7)) * 8;                  // rows 0..63
  const int r1 = (tid + 512) >> 3, c1 = (((tid + 512) & 7) ^ (r1 & 7)) * 8;  // 64..127

#define STA(buf, half, kt)                                                     \
  { char* d = smem + (buf) * 32768 + (half) * 16384;                           \
    const unsigned short* s = Arow + (size_t)((half) * 128) * K + (kt) * 64;   \
    ldst16(s + (size_t)r0 * K + c0, d + tid * 16);                             \
    ldst16(s + (size_t)r1 * K + c1, d + 8192 + tid * 16); }
#define STB(buf, half, kt)                                                     \
  { char* d = smem + 65536 + (buf) * 32768 + (half) * 16384;                   \
    const unsigned short* s = Brow + (size_t)((half) * 128) * K + (kt) * 64;   \
    ldst16(s + (size_t)r0 * K + c0, d + tid * 16);                             \
    ldst16(s + (size_t)r1 * K + c1, d + 8192 + tid * 16); }

  f32x4 acc[8][4];
#pragma unroll
  for (int i = 0; i < 8; ++i)
#pragma unroll
    for (int j = 0; j < 4; ++j) acc[i][j] = (f32x4){0.f, 0.f, 0.f, 0.f};

  // prologue: kt0 (A+B) + B(kt1). A(kt1) staged at kt0-p0.
  STA(0, 0, 0); STA(0, 1, 0); STB(0, 0, 0); STB(0, 1, 0);
  STB(1, 0, 1); STB(1, 1, 1);
  asm volatile("s_waitcnt vmcnt(4)" ::: "memory");   // kt0 fully in LDS
  __builtin_amdgcn_s_barrier();

  const int NKT = K >> 6;
  for (int kt = 0; kt < NKT; ++kt) {
    const int cb = kt & 1, nb = cb ^ 1;
    const char* Ab = smem + cb * 32768;
    const char* Bb = smem + 65536 + cb * 32768;
    bf16x8 bfr[4][2];

#pragma unroll
    for (int p = 0; p < 4; ++p) {
      // ds_read this phase's fragments
      bf16x8 af[2][2];
#pragma unroll
      for (int i = 0; i < 2; ++i)
#pragma unroll
        for (int kk = 0; kk < 2; ++kk) {
          int r = wm * 128 + (2 * p + i) * 16 + q;
          af[i][kk] = *(const bf16x8*)(Ab + r * 128 + SWZ(r, kk * 64 + g * 16));
        }
      if (p == 0) {
#pragma unroll
        for (int nr = 0; nr < 4; ++nr)
#pragma unroll
          for (int kk = 0; kk < 2; ++kk) {
            int r = wn * 64 + nr * 16 + q;
            bfr[nr][kk] = *(const bf16x8*)(Bb + r * 128 + SWZ(r, kk * 64 + g * 16));
          }
      }

      // stage (regions freed by retirement analysis)
      if (p == 0)      { if (kt + 1 < NKT) { STA(nb, 0, kt + 1); STA(nb, 1, kt + 1); } }
      else if (p == 1) { if (kt + 2 < NKT) STB(cb, 0, kt + 2); }
      else if (p == 2) { if (kt + 2 < NKT) STB(cb, 1, kt + 2); }

      __builtin_amdgcn_s_barrier();
      __builtin_amdgcn_s_setprio(1);
#pragma unroll
      for (int i = 0; i < 2; ++i)
#pragma unroll
        for (int nr = 0; nr < 4; ++nr)
#pragma unroll
          for (int kk = 0; kk < 2; ++kk)
            acc[2 * p + i][nr] = __builtin_amdgcn_mfma_f32_16x16x32_bf16(
                bfr[nr][kk], af[i][kk], acc[2 * p + i][nr], 0, 0, 0);
      __builtin_amdgcn_s_setprio(0);

      if (p == 3) {
        if (kt + 2 < NKT) { asm volatile("s_waitcnt vmcnt(4)" ::: "memory"); }
        else              { asm volatile("s_waitcnt vmcnt(0)" ::: "memory"); }
      }
      __builtin_amdgcn_s_barrier();
    }
  }

  // epilogue
  const int g4 = g * 4;
#pragma unroll
  for (int mr = 0; mr < 8; ++mr) {
    int row = m0 + wm * 128 + mr * 16 + q;
#pragma unroll
    for (int nr = 0; nr < 4; ++nr) {
      int colb = n0 + wn * 64 + nr * 16 + g4;
      float4 bv = *(const float4*)(bias + colb);
      f32x4 v = acc[mr][nr];
      float v0 = v[0] + bv.x, v1 = v[1] + bv.y, v2 = v[2] + bv.z, v3 = v[3] + bv.w;
      if (EPI == 1) {
        float o[4] = {v0, v1, v2, v3};
#pragma unroll
        for (int j = 0; j < 4; ++j) {
          float u = 0.7978845608028654f * (o[j] + 0.044715f * o[j] * o[j] * o[j]);
          float e = __expf(2.f * u);
          float th = 1.f - 2.f / (e + 1.f);
          o[j] = 0.5f * o[j] * (1.f + th);
        }
        uint2 w = {cvt_pk(o[0], o[1]), cvt_pk(o[2], o[3])};
        *(uint2*)((unsigned short*)Cp + (size_t)row * N + colb) = w;
      } else {  // EPI == 2: KV split
        if (n0 < 1024) {
          uint2 w = {cvt_pk(v0, v1), cvt_pk(v2, v3)};
          *(uint2*)((unsigned short*)Cp + (size_t)row * 1024 + colb) = w;
        } else {
          int b = row >> 12, s = row & 4095;
          int d0 = colb - 1024;
          unsigned short* vt = C2 + ((size_t)b * DIM + d0) * SS + s;
          vt[0] = f2bf(v0);
          vt[SS] = f2bf(v1);
          vt[2 * SS] = f2bf(v2);
          vt[3 * SS] = f2bf(v3);
        }
      }
    }
  }
#undef STA
#undef STB
}

// ---------------------------------------------------------------------------
// Flash attention v4 (swapped-operand, no-max softmax, 512 threads).
// Triple-buffered K/V: stage t+2 during t; raw s_barrier + vmcnt(2).
// Grid 512 linear: b = bid&7 (batch->XCD), qt = (bid>>3)&3, h = bid>>5.
// ---------------------------------------------------------------------------
__global__ __launch_bounds__(512, 4)
void attn_kernel4(const unsigned short* __restrict__ Qb,
                  const unsigned short* __restrict__ Kb,
                  const unsigned short* __restrict__ Vt,
                  unsigned short* __restrict__ Ob) {
  __shared__ char smem[81920];
  // Qs 0..16K | Ks 3 bufs @16K+j*8K | Vs 3 bufs @40K+j*8K | Ps 64K (8x2KB)

  const int tid = threadIdx.x, lane = tid & 63, wave = tid >> 6;
  const int bid = blockIdx.x;
  const int b = bid & 7, qt = (bid >> 3) & 3, h = bid >> 5;
  const int q0 = qt * 128;
  const int q = lane & 15, g = lane >> 4;

  const int rK = tid >> 3;
  const int cK = (tid & 7) ^ (rK & 7);
  char* const Pw = smem + 65536 + wave * 2048;

  const unsigned short* srcQ = Qb + ((size_t)b * TT + q0) * DIM + h * HDIM;
  const unsigned short* srcK = Kb + (size_t)b * SS * DIM + h * HDIM;
  const unsigned short* srcV = Vt + ((size_t)b * DIM + h * HDIM) * SS;

  {
    int r = tid >> 3, c = (tid & 7) ^ (r & 7);
    ldst16(srcQ + (size_t)r * DIM + c * 8, smem + tid * 16);
    int ch = tid + 512;
    r = ch >> 3; c = (ch & 7) ^ (r & 7);
    ldst16(srcQ + (size_t)r * DIM + c * 8, smem + ch * 16);
  }
  ldst16(srcK + (size_t)rK * DIM + cK * 8, smem + 16384 + tid * 16);
  ldst16(srcV + (size_t)rK * SS + cK * 8, smem + 40960 + tid * 16);
  ldst16(srcK + (size_t)(64 + rK) * DIM + cK * 8, smem + 24576 + tid * 16);
  ldst16(srcV + (size_t)rK * SS + 64 + cK * 8, smem + 49152 + tid * 16);
  asm volatile("s_waitcnt vmcnt(2)" ::: "memory");   // Q + tile0 done
  __builtin_amdgcn_s_barrier();

  bf16x8 qf[2];
  {
    int r = wave * 16 + q;
    qf[0] = *(const bf16x8*)(smem + r * 128 + SWZ(r, g * 16));
    qf[1] = *(const bf16x8*)(smem + r * 128 + SWZ(r, 64 + g * 16));
  }

  f32x4 acc[4];
#pragma unroll
  for (int dt = 0; dt < 4; ++dt) acc[dt] = (f32x4){0.f, 0.f, 0.f, 0.f};
  float lsum = 0.f;
  const float CSC = 0.125f * 1.4426950408889634f;

  const int NT = SS / 64;
  int cur = 0, sb = 2;
  for (int t = 0; t < NT; ++t) {
    char* Kc = smem + 16384 + cur * 8192;
    char* Vc = smem + 40960 + cur * 8192;
    if (t + 2 < NT) {
      char* Kn = smem + 16384 + sb * 8192;
      char* Vn = smem + 40960 + sb * 8192;
      ldst16(srcK + (size_t)((t + 2) * 64 + rK) * DIM + cK * 8, Kn + tid * 16);
      ldst16(srcV + (size_t)rK * SS + (t + 2) * 64 + cK * 8, Vn + tid * 16);
    }

    f32x4 st[4];
#pragma unroll
    for (int si = 0; si < 4; ++si) st[si] = (f32x4){0.f, 0.f, 0.f, 0.f};
#pragma unroll
    for (int kk = 0; kk < 2; ++kk)
#pragma unroll
      for (int si = 0; si < 4; ++si) {
        int r = si * 16 + q;
        bf16x8 kf = *(const bf16x8*)(Kc + r * 128 + SWZ(r, kk * 64 + g * 16));
        st[si] = __builtin_amdgcn_mfma_f32_16x16x32_bf16(kf, qf[kk], st[si], 0, 0, 0);
      }

    float rs = 0.f;
#pragma unroll
    for (int si = 0; si < 4; ++si) {
      float p0 = __builtin_amdgcn_exp2f(st[si][0] * CSC);
      float p1 = __builtin_amdgcn_exp2f(st[si][1] * CSC);
      float p2 = __builtin_amdgcn_exp2f(st[si][2] * CSC);
      float p3 = __builtin_amdgcn_exp2f(st[si][3] * CSC);
      rs += (p0 + p1) + (p2 + p3);
      uint2 w = {cvt_pk(p0, p1), cvt_pk(p2, p3)};
      *(uint2*)(Pw + q * 128 + SWZ(q, si * 32 + g * 8)) = w;
    }
    lsum += rs;

#pragma unroll
    for (int kk = 0; kk < 2; ++kk) {
      bf16x8 pb = *(const bf16x8*)(Pw + q * 128 + SWZ(q, kk * 64 + g * 16));
#pragma unroll
      for (int dt = 0; dt < 4; ++dt) {
        int r = dt * 16 + q;
        bf16x8 va = *(const bf16x8*)(Vc + r * 128 + SWZ(r, kk * 64 + g * 16));
        acc[dt] = __builtin_amdgcn_mfma_f32_16x16x32_bf16(va, pb, acc[dt], 0, 0, 0);
      }
    }

    if (t + 2 < NT) { asm volatile("s_waitcnt vmcnt(2)" ::: "memory"); }
    else            { asm volatile("s_waitcnt vmcnt(0)" ::: "memory"); }
    __builtin_amdgcn_s_barrier();
    cur = cur == 2 ? 0 : cur + 1;
    sb  = sb  == 2 ? 0 : sb  + 1;
  }

  lsum += __shfl_xor(lsum, 16);
  lsum += __shfl_xor(lsum, 32);
  float inv = 1.0f / lsum;
#pragma unroll
  for (int dt = 0; dt < 4; ++dt) {
    f32x4 v = acc[dt];
    uint2 w = {cvt_pk(v[0] * inv, v[1] * inv), cvt_pk(v[2] * inv, v[3] * inv)};
    *(uint2*)(Pw + q * 128 + SWZ(q, dt * 32 + g * 8)) = w;
  }
  __builtin_amdgcn_s_waitcnt(0);
  int qr = lane >> 2, cb = (lane & 3) * 32;
  uint4 lo = *(const uint4*)(Pw + qr * 128 + SWZ(qr, cb));
  uint4 hi = *(const uint4*)(Pw + qr * 128 + SWZ(qr, cb + 16));
  size_t ob = ((size_t)b * TT + q0 + wave * 16 + qr) * DIM + h * HDIM + (lane & 3) * 16;
  *(uint4*)(Ob + ob) = lo;
  *(uint4*)(Ob + ob + 8) = hi;
}

// ---------------------------------------------------------------------------
// host
// ---------------------------------------------------------------------------
extern "C" void kernel_launch(void* const* d_in, const int* in_sizes, int n_in,
                              void* d_out, int out_size, void* d_ws, size_t ws_size,
                              hipStream_t stream) {
  const float* x   = (const float*)d_in[0];
  const float* inp = (const float*)d_in[1];
  const float* Wq  = (const float*)d_in[2];
  const float* bq  = (const float*)d_in[3];
  const float* Wk  = (const float*)d_in[4];
  const float* bk  = (const float*)d_in[5];
  const float* Wv  = (const float*)d_in[6];
  const float* bv  = (const float*)d_in[7];
  const float* Wo  = (const float*)d_in[8];
  const float* bo  = (const float*)d_in[9];
  const float* W1  = (const float*)d_in[10];
  const float* b1  = (const float*)d_in[11];
  const float* W2  = (const float*)d_in[12];
  const float* b2  = (const float*)d_in[13];
  float* out = (float*)d_out;

  // workspace (MB): 0-2 Wqt | 2-6 Wkvt | 6-8 Wot | 8-16 W1t | 16-24 W2t |
  // 24 bkv | 25-33 Qb | 33-97 Kb | 97-161 Vt | 161-225 inpb | 225-233 xb
  // post-attn: x2 33-49 (f32) | x2b 49-57 | hb 57-89. Obf aliases d_out.
  char* ws = (char*)d_ws;
  const size_t MB = 1024ull * 1024ull;
  unsigned short* Wqt  = (unsigned short*)(ws + 0 * MB);
  unsigned short* Wkvt = (unsigned short*)(ws + 2 * MB);     // [2048][1024]
  unsigned short* Wot  = (unsigned short*)(ws + 6 * MB);
  unsigned short* W1t  = (unsigned short*)(ws + 8 * MB);
  unsigned short* W2t  = (unsigned short*)(ws + 16 * MB);
  float*          bkv  = (float*)(ws + 24 * MB);
  unsigned short* Qb   = (unsigned short*)(ws + 25 * MB);
  unsigned short* Kb   = (unsigned short*)(ws + 33 * MB);
  float*          x2   = (float*)(ws + 33 * MB);             // post-attn alias
  unsigned short* x2b  = (unsigned short*)(ws + 49 * MB);
  unsigned short* hb   = (unsigned short*)(ws + 57 * MB);
  unsigned short* Vt   = (unsigned short*)(ws + 97 * MB);
  unsigned short* inpb = (unsigned short*)(ws + 161 * MB);
  unsigned short* xb   = (unsigned short*)(ws + 225 * MB);
  unsigned short* Obf  = (unsigned short*)d_out;

  // single prep launch: converts + transposes + bias concat
  prep_kernel<<<dim3(14593), 256, 0, stream>>>(x, inp, Wq, Wk, Wv, Wo, W1, W2,
                                               bk, bv, xb, inpb, Wqt, Wkvt,
                                               Wot, W1t, W2t, bkv);

  // Q projection (128^2)
  gemm_kernel<0><<<dim3(8, 32), 256, 0, stream>>>(xb, Wqt, bq, nullptr, Qb, nullptr, BB * TT, DIM, DIM);
  // fused KV projection (256^2 4-phase): K-half -> Kb, V-half -> Vt transposed
  gemm256<2><<<dim3(8, 128), 512, 0, stream>>>(inpb, Wkvt, bkv, Kb, Vt, BB * SS, 2048, DIM);

  attn_kernel4<<<dim3(512), 512, 0, stream>>>(Qb, Kb, Vt, Obf);

  // O projection + residual -> x2 (f32) + x2b (bf16)
  gemm_kernel<3><<<dim3(8, 32), 256, 0, stream>>>(Obf, Wot, bo, x, x2, x2b, BB * TT, DIM, DIM);
  // MLP1 (256^2 4-phase, GELU)
  gemm256<1><<<dim3(16, 16), 512, 0, stream>>>(x2b, W1t, b1, hb, nullptr, BB * TT, FF_, DIM);
  // MLP2 (128^2, +res f32)
  gemm_kernel<2><<<dim3(8, 32), 256, 0, stream>>>(hb, W2t, b2, x2, out, nullptr, BB * TT, DIM, FF_);
}